// Round 6
// baseline (54.248 us; speedup 1.0000x reference)
//
#include <hip/hip_runtime.h>
#include <utility>

// NCC loss, streaming: full-row C=8, (I,J)-packed fp16, GLOBAL_LOAD_LDS
// PIPELINE. I,J fp32 (32,1,512,512), 9x9 box, zero-pad, /81.
// History: R21 42.3us (prefetch-1, VALUBusy 16%, latency convoy). R22 source
// ring FAILED (compiler sank issues). R23 2-wave FAILED (convoy TLP-
// invariant). R24-R26 asm-register pipelines FAILED: 16 asm-pinned f4 buffers
// (can't split/remat/AGPR-place) force >256 VGPR demand -> scratch spills
// (VGPR=256, WRITE_SIZE 11-15MB) regardless of moving rings to LDS.
// R27: in-flight data moves to LDS via __builtin_amdgcn_global_load_lds
// (async, vmcnt-tracked, ZERO VGPR while in flight — the cp.async analog).
// LDS ring PFD=8 rows x 4KB = 32KB/block (4 blk/CU = 128 <= 160KB). Steady
// 32 ops in flight (32KB/wave, ~32MB chip >> 5.7MB BDP -> HBM saturates).
// Consume: literal vmcnt(28) + sched_barrier(0) (rule #18), ds_read_b128 x4
// (16B lane stride, conflict-free), pack, reissue slot for row y+8 (write
// lands >=200cyc later; ds_reads ordered before by aliasing -> no WAR).
// Rings rg/d9 back in registers (R21-proven fit via AGPR overflow; no asm
// "v" constraints remain to block the allocator). Tail vmcnt 28/24/../0.
// DPP bound_ctrl edge zeros == image zero-padding; cross-term via d*swap(d);
// rings store rounded h2 once (add==evict bits -> telescoping).

constexpr int BATCH = 32;
constexpr int H = 512, W = 512;
constexpr int YB = 16;
constexpr int NBAND = H / YB;   // 32
constexpr int NSTEP = YB + 16;  // 32 raw rows yb-8 .. yb+23
constexpr int PFD = 8;          // prefetch distance (rows); 4 gld_lds/row
constexpr float EPS81 = 81.0f * 81.0f * 1e-5f;  // ncc = R^2/(P*Q+EPS81)

using h2 = __attribute__((ext_vector_type(2))) _Float16;

__global__ void zero_accum(float* ws) { ws[0] = 0.0f; }

__device__ __forceinline__ h2 up1(h2 x) {  // lane i <- i-1 (wave_shr:1), edge=0
  return __builtin_bit_cast(
      h2, __builtin_amdgcn_update_dpp(0, __builtin_bit_cast(int, x), 0x138, 0xF,
                                      0xF, true));
}
__device__ __forceinline__ h2 dn1(h2 x) {  // lane i <- i+1 (wave_shl:1), edge=0
  return __builtin_bit_cast(
      h2, __builtin_amdgcn_update_dpp(0, __builtin_bit_cast(int, x), 0x130, 0xF,
                                      0xF, true));
}
// pack (I,J) -> h2 (RTZ) then AND-mask (wave-uniform y zero-pad)
__device__ __forceinline__ h2 pkm(float lo, float hi, unsigned m) {
  const unsigned u =
      __builtin_bit_cast(unsigned, __builtin_amdgcn_cvt_pkrtz(lo, hi)) & m;
  return __builtin_bit_cast(h2, u);
}
__device__ __forceinline__ h2 swp(h2 x) {  // swap halves (folds to op_sel)
  return __builtin_shufflevector(x, x, 1, 0);
}

// Async 16B/lane global->LDS. Dest = uniform base + lane*16 (HW-fixed);
// src is per-lane. No VGPR holds the in-flight data; tracked by vmcnt.
__device__ __forceinline__ void gld16(const float* g, float* l) {
  __builtin_amdgcn_global_load_lds(
      (const __attribute__((address_space(1))) void*)g,
      (__attribute__((address_space(3))) void*)l, 16, 0, 0);
}

// Stage one image row pair (I,J) into an LDS slot: 4 vmem ops.
// Slot layout: sI[0..511] = I row floats, sJ[0..511] = J row floats.
__device__ __forceinline__ void stage_row(const float* gI, const float* gJ,
                                          float* sI, float* sJ, int lane) {
  gld16(gI + 4 * lane, sI);              // floats [0,256): lane l -> [4l,4l+4)
  gld16(gI + 256 + 4 * lane, sI + 256);  // floats [256,512)
  gld16(gJ + 4 * lane, sJ);
  gld16(gJ + 256 + 4 * lane, sJ + 256);
}

// Hand-counted wait + rule-#18 fence (consumers may not hoist above).
template <int N>
__device__ __forceinline__ void waitcnt_vm() {
  asm volatile("s_waitcnt vmcnt(%0)" ::"i"(N) : "memory");
  __builtin_amdgcn_sched_barrier(0);
}

template <class F, int... Ks>
__device__ __forceinline__ void unroll_steps(F&& f,
                                             std::integer_sequence<int, Ks...>) {
  (f(std::integral_constant<int, Ks>{}), ...);
}

// 9-tap centered window sums, 8 contiguous cols/lane (whole 512-col row).
__device__ __forceinline__ void tap8(const h2 u[8], h2 O[8]) {
  const h2 P0 = u[0], P1 = P0 + u[1], P2 = P1 + u[2], P3 = P2 + u[3],
           P4 = P3 + u[4], P5 = P4 + u[5], P6 = P5 + u[6], T = P6 + u[7];
  const h2 UP3 = up1(P3), UP4 = up1(P4), UP5 = up1(P5), UP6 = up1(P6), UT = up1(T);
  const h2 DP0 = dn1(P0), DP1 = dn1(P1), DP2 = dn1(P2), DP3 = dn1(P3);
  O[0] = (UT - UP3) + P4;
  O[1] = (UT - UP4) + P5;
  O[2] = (UT - UP5) + P6;
  O[3] = (UT - UP6) + T;
  O[4] = T + DP0;
  O[5] = (T - P0) + DP1;
  O[6] = (T - P1) + DP2;
  O[7] = (T - P2) + DP3;
}

__global__ __launch_bounds__(64, 1) void ncc_stream(const float* __restrict__ I,
                                                    const float* __restrict__ J,
                                                    float* __restrict__ accum) {
  const int lane = threadIdx.x;
  const int blk = blockIdx.x;
  const int band = blk & (NBAND - 1);
  const int b = blk >> 5;  // batch 0..31
  const int yb = band * YB;
  const h2 zero2 = {_Float16(0.0f), _Float16(0.0f)};
  const h2 ninv81 = {_Float16(-1.0f / 81.0f), _Float16(-1.0f / 81.0f)};

  const float* __restrict__ Ib = I + (size_t)b * (H * W);
  const float* __restrict__ Jb = J + (size_t)b * (H * W);

  // LDS staging ring: [slot][img][col]; 8 x 2 x 512 x 4B = 32 KB.
  __shared__ __align__(16) float stg[PFD][2][512];

  // mod-9 rings (packed I,J), all indices compile-time in the unrolled body
  h2 rg[9][8];   // raw ring: (I, J)
  h2 d9[9][8];   // dI/dJ ring: (dI, dJ)
  h2 V[8];       // running vertical sum of raw
  h2 vpq[8];     // (sum dI^2, sum dJ^2)
  h2 vr[8];      // (sum dI*dJ, same)
#pragma unroll
  for (int s = 0; s < 9; ++s)
#pragma unroll
    for (int c = 0; c < 8; ++c) { rg[s][c] = zero2; d9[s][c] = zero2; }
#pragma unroll
  for (int c = 0; c < 8; ++c) { V[c] = zero2; vpq[c] = zero2; vr[c] = zero2; }
  float acc = 0.f;

  // Prologue: stage rows yb-8 .. yb-1 (lower clamp only; max 495).
#pragma unroll
  for (int j = 0; j < PFD; ++j) {
    const int y0 = yb - 8 + j;
    const int yc0 = y0 < 0 ? 0 : y0;
    const int off0 = yc0 * W;
    stage_row(Ib + off0, Jb + off0, &stg[j][0][0], &stg[j][1][0], lane);
  }

  // k=0..31: y = yb-8+k. k>=8: stage1 at m=y-4. k>=16: stage2 + output o=y-8.
  unroll_steps(
      [&](auto kc) {
        constexpr int K = decltype(kc)::value;
        constexpr int si = K % 9;        // data ring slot
        constexpr int t = (si + 5) % 9;  // center slot
        constexpr int sl = K % PFD;      // staging ring slot
        constexpr int REM = NSTEP - 1 - K;
        constexpr int ALW = 4 * (REM < PFD - 1 ? REM : PFD - 1);
        const int y = yb - 8 + K;
        const unsigned msk = ((y >= 0) & (y < H)) ? 0xFFFFFFFFu : 0u;

        // 0) wait until slot sl's 4 gld_lds (issued PFD steps ago) landed;
        //    leaves ALW (steady 28) in flight.
        waitcnt_vm<ALW>();

        // 1) consume slot sl from LDS (b128 x4, 16B stride conflict-free),
        //    pack (I,J), AND-mask y-pad
        const float4 ia = *reinterpret_cast<const float4*>(&stg[sl][0][8 * lane]);
        const float4 ic = *reinterpret_cast<const float4*>(&stg[sl][0][8 * lane + 4]);
        const float4 ja = *reinterpret_cast<const float4*>(&stg[sl][1][8 * lane]);
        const float4 jc = *reinterpret_cast<const float4*>(&stg[sl][1][8 * lane + 4]);
        h2 na[8];
        na[0] = pkm(ia.x, ja.x, msk);
        na[1] = pkm(ia.y, ja.y, msk);
        na[2] = pkm(ia.z, ja.z, msk);
        na[3] = pkm(ia.w, ja.w, msk);
        na[4] = pkm(ic.x, jc.x, msk);
        na[5] = pkm(ic.y, jc.y, msk);
        na[6] = pkm(ic.z, jc.z, msk);
        na[7] = pkm(ic.w, jc.w, msk);

        // 2) reissue slot sl for row y+PFD (clamped addr; mask fixes values).
        //    Aliases the ds_reads above -> compiler keeps order; write lands
        //    >=200cyc after issue anyway.
        if constexpr (K + PFD < NSTEP) {
          const int yn = y + PFD;
          const int ycn = yn > H - 1 ? H - 1 : yn;  // yn >= yb >= 0
          const int offn = ycn * W;
          stage_row(Ib + offn, Jb + offn, &stg[sl][0][0], &stg[sl][1][0], lane);
        }

        // 3) vertical running sum: evict slot si (row y-9), write new
#pragma unroll
        for (int c = 0; c < 8; ++c) {
          V[c] += na[c] - rg[si][c];
          rg[si][c] = na[c];
        }

        if constexpr (K >= 8) {
          const int m = y - 4;
          if ((m >= 0) & (m < H)) {  // wave-uniform
            h2 M[8];
            tap8(V, M);
#pragma unroll
            for (int c = 0; c < 8; ++c) {
              const h2 d = M[c] * ninv81 + rg[t][c];  // (dI, dJ)
              const h2 o = d9[t][c];
              vpq[c] += d * d - o * o;                // (dI^2, dJ^2)
              vr[c] += d * swp(d) - o * swp(o);       // (dI*dJ, dI*dJ)
              d9[t][c] = d;
            }
          } else {  // m outside image: dI=dJ=0, eviction-only
#pragma unroll
            for (int c = 0; c < 8; ++c) {
              const h2 o = d9[t][c];
              vpq[c] -= o * o;
              vr[c] -= o * swp(o);
              d9[t][c] = zero2;
            }
          }

          if constexpr (K >= 16) {
            h2 P[8], R[8];
            tap8(vpq, P);  // (81^2 varI, 81^2 varJ) pre-scale
            tap8(vr, R);   // (81^2 cov, same)
#pragma unroll
            for (int c = 0; c < 8; ++c) {
              const float Pl = (float)P[c][0], Qh = (float)P[c][1];
              const float Rl = (float)R[c][0];
              acc += (Rl * Rl) * __builtin_amdgcn_rcpf(fmaf(Pl, Qh, EPS81));
            }
          }
        }
      },
      std::make_integer_sequence<int, NSTEP>{});

  // wave reduction, one atomic per wave
#pragma unroll
  for (int off = 32; off > 0; off >>= 1) acc += __shfl_down(acc, off, 64);
  if (lane == 0) atomicAdd(accum, acc);
}

__global__ void finalize(const float* __restrict__ ws, float* __restrict__ out) {
  out[0] = -ws[0] * (1.0f / (float)((size_t)BATCH * H * W));
}

extern "C" void kernel_launch(void* const* d_in, const int* in_sizes, int n_in,
                              void* d_out, int out_size, void* d_ws, size_t ws_size,
                              hipStream_t stream) {
  const float* I = (const float*)d_in[0];
  const float* J = (const float*)d_in[1];
  float* out = (float*)d_out;
  float* acc = (float*)d_ws;

  zero_accum<<<1, 1, 0, stream>>>(acc);
  ncc_stream<<<BATCH * NBAND, 64, 0, stream>>>(I, J, acc);
  finalize<<<1, 1, 0, stream>>>(acc, out);
}

// Round 7
// 50.846 us; speedup vs baseline: 1.0669x; 1.0669x over previous
//
#include <hip/hip_runtime.h>
#include <utility>

// NCC loss, streaming: full-row C=8, (I,J)-packed fp16, GLOBAL_LOAD_LDS
// PIPELINE v2 (state diet). I,J fp32 (32,1,512,512), 9x9 box, zero-pad, /81.
// History: R21 42.3us (prefetch-1 convoy, VALUBusy 16%). R22 source ring
// FAILED (compiler sank issues). R23 2-wave FAILED (convoy TLP-invariant).
// R24-26 asm-reg pipelines FAILED (VGPR 256 + scratch). R27 gld_lds kept
// rings in regs: STILL 256/13.8MB scratch -> resident state rg+d9+temps
// straddles 256 once asm fractures the schedule; also 32B-stride float4
// LDS reads = 524K bank conflicts.
// R28: cut 72 arch regs — rg ring becomes a packed h2 LDS ring pkr[10]
// (write na @ K%10, evict read @ (K+1)%10 = row y-9, center read @ (K+6)%10
// = row y-4; K literal -> all static). ALL LDS at 16B lane stride (u4
// [..][64]) = R26's measured-zero-conflict pattern, incl. staging: global
// src pre-swizzled (+8*lane / +8*lane+4) so b128 reads are lane-major.
// Staging PFD=4 rows x (I,J) x 2 halves = 16KB; pkr 20KB; total 36KB ->
// 4 blk/CU = 144KB, all 1024 waves resident, 16KB/wave in flight (~16MB
// chip >> ~6MB BDP). Steady vmcnt(12), tail 12/8/4/0; no sched_barrier
// (consumers are memory ops, ordered by "memory" clobber). Reg state:
// d9(72)+V/vpq/vr(24)+na(8)+temps ~ 160 peak -> no spills.
// DPP bound_ctrl edge zeros == image zero-padding; cross-term via d*swap(d);
// rings store rounded h2 once (add==evict bits -> telescoping).

constexpr int BATCH = 32;
constexpr int H = 512, W = 512;
constexpr int YB = 16;
constexpr int NBAND = H / YB;   // 32
constexpr int NSTEP = YB + 16;  // 32 raw rows yb-8 .. yb+23
constexpr int PFD = 4;          // prefetch distance (rows); 4 gld_lds/row
constexpr int RING = 10;        // packed-row ring depth (y-9 .. y)
constexpr float EPS81 = 81.0f * 81.0f * 1e-5f;  // ncc = R^2/(P*Q+EPS81)

using h2 = __attribute__((ext_vector_type(2))) _Float16;
using u4 = __attribute__((ext_vector_type(4))) unsigned int;

__global__ void zero_accum(float* ws) { ws[0] = 0.0f; }

__device__ __forceinline__ h2 up1(h2 x) {  // lane i <- i-1 (wave_shr:1), edge=0
  return __builtin_bit_cast(
      h2, __builtin_amdgcn_update_dpp(0, __builtin_bit_cast(int, x), 0x138, 0xF,
                                      0xF, true));
}
__device__ __forceinline__ h2 dn1(h2 x) {  // lane i <- i+1 (wave_shl:1), edge=0
  return __builtin_bit_cast(
      h2, __builtin_amdgcn_update_dpp(0, __builtin_bit_cast(int, x), 0x130, 0xF,
                                      0xF, true));
}
// pack (I,J) -> h2 (RTZ) then AND-mask (wave-uniform y zero-pad)
__device__ __forceinline__ h2 pkm(float lo, float hi, unsigned m) {
  const unsigned u =
      __builtin_bit_cast(unsigned, __builtin_amdgcn_cvt_pkrtz(lo, hi)) & m;
  return __builtin_bit_cast(h2, u);
}
__device__ __forceinline__ h2 swp(h2 x) {  // swap halves (folds to op_sel)
  return __builtin_shufflevector(x, x, 1, 0);
}

// Async 16B/lane global->LDS. LDS dest = wave-uniform base + lane*16 (HW);
// global src is PER-LANE -> pre-swizzle src so lane-major LDS layout holds
// the cols this lane computes. No VGPR holds in-flight data; vmcnt-tracked.
__device__ __forceinline__ void gld16(const float* g, u4* l) {
  __builtin_amdgcn_global_load_lds(
      (const __attribute__((address_space(1))) void*)g,
      (__attribute__((address_space(3))) void*)l, 16, 0, 0);
}

// Stage one (I,J) row pair into staging slot s: 4 vmem ops.
// slot layout: [img][half][lane] u4 ; lane l half0 = cols 8l..8l+3,
// half1 = cols 8l+4..8l+7 (src pre-swizzled by +8*lane).
__device__ __forceinline__ void stage_row(const float* gI, const float* gJ,
                                          u4 (*slot)[2][64], int lane) {
  gld16(gI + 8 * lane, &slot[0][0][0]);
  gld16(gI + 8 * lane + 4, &slot[0][1][0]);
  gld16(gJ + 8 * lane, &slot[1][0][0]);
  gld16(gJ + 8 * lane + 4, &slot[1][1][0]);
}

// Hand-counted wait; "memory" clobber orders the following ds_reads.
template <int N>
__device__ __forceinline__ void waitcnt_vm() {
  asm volatile("s_waitcnt vmcnt(%0)" ::"i"(N) : "memory");
}

template <class F, int... Ks>
__device__ __forceinline__ void unroll_steps(F&& f,
                                             std::integer_sequence<int, Ks...>) {
  (f(std::integral_constant<int, Ks>{}), ...);
}

// 9-tap centered window sums, 8 contiguous cols/lane (whole 512-col row).
__device__ __forceinline__ void tap8(const h2 u[8], h2 O[8]) {
  const h2 P0 = u[0], P1 = P0 + u[1], P2 = P1 + u[2], P3 = P2 + u[3],
           P4 = P3 + u[4], P5 = P4 + u[5], P6 = P5 + u[6], T = P6 + u[7];
  const h2 UP3 = up1(P3), UP4 = up1(P4), UP5 = up1(P5), UP6 = up1(P6), UT = up1(T);
  const h2 DP0 = dn1(P0), DP1 = dn1(P1), DP2 = dn1(P2), DP3 = dn1(P3);
  O[0] = (UT - UP3) + P4;
  O[1] = (UT - UP4) + P5;
  O[2] = (UT - UP5) + P6;
  O[3] = (UT - UP6) + T;
  O[4] = T + DP0;
  O[5] = (T - P0) + DP1;
  O[6] = (T - P1) + DP2;
  O[7] = (T - P2) + DP3;
}

__global__ __launch_bounds__(64, 1) void ncc_stream(const float* __restrict__ I,
                                                    const float* __restrict__ J,
                                                    float* __restrict__ accum) {
  const int lane = threadIdx.x;
  const int blk = blockIdx.x;
  const int band = blk & (NBAND - 1);
  const int b = blk >> 5;  // batch 0..31
  const int yb = band * YB;
  const h2 zero2 = {_Float16(0.0f), _Float16(0.0f)};
  const h2 ninv81 = {_Float16(-1.0f / 81.0f), _Float16(-1.0f / 81.0f)};

  const float* __restrict__ Ib = I + (size_t)b * (H * W);
  const float* __restrict__ Jb = J + (size_t)b * (H * W);

  // LDS: staging ring [slot][img][half][lane] u4 = 16KB; packed h2 ring
  // [slot][half][lane] u4 = 20KB. All accesses 16B lane stride (0-conflict).
  __shared__ u4 stg[PFD][2][2][64];
  __shared__ u4 pkr[RING][2][64];

  h2 d9[9][8];  // dI/dJ ring (registers)
  h2 V[8];      // running vertical sum of raw
  h2 vpq[8];    // (sum dI^2, sum dJ^2)
  h2 vr[8];     // (sum dI*dJ, same)
#pragma unroll
  for (int s = 0; s < 9; ++s)
#pragma unroll
    for (int c = 0; c < 8; ++c) d9[s][c] = zero2;
#pragma unroll
  for (int c = 0; c < 8; ++c) { V[c] = zero2; vpq[c] = zero2; vr[c] = zero2; }
  const u4 zero4 = {0u, 0u, 0u, 0u};
#pragma unroll
  for (int s = 0; s < RING; ++s) {
    pkr[s][0][lane] = zero4;
    pkr[s][1][lane] = zero4;
  }
  float acc = 0.f;

  // Prologue: stage rows yb-8 .. yb-5 (lower clamp only; max 491).
#pragma unroll
  for (int j = 0; j < PFD; ++j) {
    const int y0 = yb - 8 + j;
    const int yc0 = y0 < 0 ? 0 : y0;
    const int off0 = yc0 * W;
    stage_row(Ib + off0, Jb + off0, stg[j], lane);
  }

  // k=0..31: y = yb-8+k. k>=8: stage1 at m=y-4. k>=16: stage2 + output o=y-8.
  unroll_steps(
      [&](auto kc) {
        constexpr int K = decltype(kc)::value;
        constexpr int si = K % 9;           // d9 write slot cycle
        constexpr int t = (si + 5) % 9;     // d9 center slot (row y-4)
        constexpr int sl = K % PFD;         // staging slot
        constexpr int pw = K % RING;        // pkr write slot (row y)
        constexpr int pe = (K + 1) % RING;  // pkr evict slot (row y-9)
        constexpr int pc = (K + 6) % RING;  // pkr center slot (row y-4)
        constexpr int REM = NSTEP - 1 - K;
        constexpr int ALW = 4 * (REM < PFD - 1 ? REM : PFD - 1);
        const int y = yb - 8 + K;
        const unsigned msk = ((y >= 0) & (y < H)) ? 0xFFFFFFFFu : 0u;

        // 0) wait for slot sl's 4 gld_lds (issued PFD steps ago);
        //    leaves ALW (steady 12) in flight.
        waitcnt_vm<ALW>();

        // 1) consume slot sl (b128 x4, 16B lane stride = conflict-free),
        //    pack (I,J), AND-mask y-pad
        const float4 ia = *reinterpret_cast<const float4*>(&stg[sl][0][0][lane]);
        const float4 ic = *reinterpret_cast<const float4*>(&stg[sl][0][1][lane]);
        const float4 ja = *reinterpret_cast<const float4*>(&stg[sl][1][0][lane]);
        const float4 jc = *reinterpret_cast<const float4*>(&stg[sl][1][1][lane]);
        h2 na[8];
        na[0] = pkm(ia.x, ja.x, msk);
        na[1] = pkm(ia.y, ja.y, msk);
        na[2] = pkm(ia.z, ja.z, msk);
        na[3] = pkm(ia.w, ja.w, msk);
        na[4] = pkm(ic.x, jc.x, msk);
        na[5] = pkm(ic.y, jc.y, msk);
        na[6] = pkm(ic.z, jc.z, msk);
        na[7] = pkm(ic.w, jc.w, msk);

        // 2) reissue slot sl for row y+PFD (both clamps: yn<0 at band 0;
        //    masked values make overshoot harmless). gld LDS-write lands at
        //    data return, long after step-1's ds_reads executed.
        if constexpr (K + PFD < NSTEP) {
          const int yn = y + PFD;
          const int ycn = yn < 0 ? 0 : (yn > H - 1 ? H - 1 : yn);
          const int offn = ycn * W;
          stage_row(Ib + offn, Jb + offn, stg[sl], lane);
        }

        // 3) packed ring: write row y; evict row y-9 into V
        {
          u4 nv0, nv1;
#pragma unroll
          for (int c = 0; c < 4; ++c) {
            nv0[c] = __builtin_bit_cast(unsigned, na[c]);
            nv1[c] = __builtin_bit_cast(unsigned, na[c + 4]);
          }
          pkr[pw][0][lane] = nv0;
          pkr[pw][1][lane] = nv1;
          const u4 e0 = pkr[pe][0][lane];
          const u4 e1 = pkr[pe][1][lane];
#pragma unroll
          for (int c = 0; c < 8; ++c) {
            const h2 old = __builtin_bit_cast(h2, c < 4 ? e0[c] : e1[c - 4]);
            V[c] += na[c] - old;
          }
        }

        if constexpr (K >= 8) {
          const int m = y - 4;
          if ((m >= 0) & (m < H)) {  // wave-uniform
            const u4 c0 = pkr[pc][0][lane];  // center raw row (I,J) packed
            const u4 c1 = pkr[pc][1][lane];
            h2 M[8];
            tap8(V, M);
#pragma unroll
            for (int c = 0; c < 8; ++c) {
              const h2 ctr = __builtin_bit_cast(h2, c < 4 ? c0[c] : c1[c - 4]);
              const h2 d = M[c] * ninv81 + ctr;  // (dI, dJ)
              const h2 o = d9[t][c];
              vpq[c] += d * d - o * o;           // (dI^2, dJ^2)
              vr[c] += d * swp(d) - o * swp(o);  // (dI*dJ, dI*dJ)
              d9[t][c] = d;
            }
          } else {  // m outside image: dI=dJ=0, eviction-only
#pragma unroll
            for (int c = 0; c < 8; ++c) {
              const h2 o = d9[t][c];
              vpq[c] -= o * o;
              vr[c] -= o * swp(o);
              d9[t][c] = zero2;
            }
          }

          if constexpr (K >= 16) {
            h2 P[8], R[8];
            tap8(vpq, P);  // (81^2 varI, 81^2 varJ) pre-scale
            tap8(vr, R);   // (81^2 cov, same)
#pragma unroll
            for (int c = 0; c < 8; ++c) {
              const float Pl = (float)P[c][0], Qh = (float)P[c][1];
              const float Rl = (float)R[c][0];
              acc += (Rl * Rl) * __builtin_amdgcn_rcpf(fmaf(Pl, Qh, EPS81));
            }
          }
        }
      },
      std::make_integer_sequence<int, NSTEP>{});

  // wave reduction, one atomic per wave
#pragma unroll
  for (int off = 32; off > 0; off >>= 1) acc += __shfl_down(acc, off, 64);
  if (lane == 0) atomicAdd(accum, acc);
}

__global__ void finalize(const float* __restrict__ ws, float* __restrict__ out) {
  out[0] = -ws[0] * (1.0f / (float)((size_t)BATCH * H * W));
}

extern "C" void kernel_launch(void* const* d_in, const int* in_sizes, int n_in,
                              void* d_out, int out_size, void* d_ws, size_t ws_size,
                              hipStream_t stream) {
  const float* I = (const float*)d_in[0];
  const float* J = (const float*)d_in[1];
  float* out = (float*)d_out;
  float* acc = (float*)d_ws;

  zero_accum<<<1, 1, 0, stream>>>(acc);
  ncc_stream<<<BATCH * NBAND, 64, 0, stream>>>(I, J, acc);
  finalize<<<1, 1, 0, stream>>>(acc, out);
}

// Round 8
// 49.143 us; speedup vs baseline: 1.1039x; 1.0347x over previous
//
#include <hip/hip_runtime.h>
#include <utility>

// NCC loss, streaming: full-row C=8, (I,J)-packed fp16, GLOBAL_LOAD_LDS
// PIPELINE v3 — ROLLED 9-step macro, PFD=9 (ring-aligned).
// I,J fp32 (32,1,512,512), 9x9 box, zero-pad, /81.
// History: R21 42.3us (prefetch-1, VGPR 136). R22 source ring FAILED
// (issues sunk). R23 2-wave FAILED (per-step invariant to TLP). R24-R28
// deep pipelines ALL spilled (VGPR 256, 8-15MB scratch): 32 fully-unrolled
// step bodies + asm fence-posts blow live ranges; scratch ops ALSO count in
// vmcnt -> counted waits poisoned -> pipeline never engaged. R28's L3-
// resident dispatches (8.4MB fetch) ran at the SAME 49us -> time is NOT
// bandwidth/DRAM-latency; it is the un-engaged pipeline.
// R29: staging ring depth = 9 = data-ring period -> ROLLED outer loop over
// 9-step macros keeps stg[j]/rg[j]/d9[(j+5)%9] static with ONE body in code
// (no 32x hoisting; reg demand back to R21 regime, AGPR overflow free —
// no asm "v" constraints anywhere). gld_lds staging (0 VGPR in flight),
// stg 36KB = 4 blk/CU, all 1024 waves resident. Steady: 36 ops in flight,
// wait vmcnt(32) retires EXACTLY the consumed slot (ops 4k..4k+3 vs issued
// 36+4k) for k=0..22 uniformly. Tail k=18..31 unrolled: literals
// 32(,k<=22 issue on),28,24,...,0 — no wasted reissues, exact drain.
// DPP bound_ctrl edge zeros == image zero-padding; cross-term via d*swap(d);
// rings store rounded h2 once (add==evict bits -> telescoping).

constexpr int BATCH = 32;
constexpr int H = 512, W = 512;
constexpr int YB = 16;
constexpr int NBAND = H / YB;   // 32
constexpr int NSTEP = YB + 16;  // 32 raw rows yb-8 .. yb+23
constexpr int PFD = 9;          // staging ring slots == data ring period
constexpr float EPS81 = 81.0f * 81.0f * 1e-5f;  // ncc = R^2/(P*Q+EPS81)

using h2 = __attribute__((ext_vector_type(2))) _Float16;
using u4 = __attribute__((ext_vector_type(4))) unsigned int;

__global__ void zero_accum(float* ws) { ws[0] = 0.0f; }

__device__ __forceinline__ h2 up1(h2 x) {  // lane i <- i-1 (wave_shr:1), edge=0
  return __builtin_bit_cast(
      h2, __builtin_amdgcn_update_dpp(0, __builtin_bit_cast(int, x), 0x138, 0xF,
                                      0xF, true));
}
__device__ __forceinline__ h2 dn1(h2 x) {  // lane i <- i+1 (wave_shl:1), edge=0
  return __builtin_bit_cast(
      h2, __builtin_amdgcn_update_dpp(0, __builtin_bit_cast(int, x), 0x130, 0xF,
                                      0xF, true));
}
// pack (I,J) -> h2 (RTZ) then AND-mask (wave-uniform y zero-pad)
__device__ __forceinline__ h2 pkm(float lo, float hi, unsigned m) {
  const unsigned u =
      __builtin_bit_cast(unsigned, __builtin_amdgcn_cvt_pkrtz(lo, hi)) & m;
  return __builtin_bit_cast(h2, u);
}
__device__ __forceinline__ h2 swp(h2 x) {  // swap halves (folds to op_sel)
  return __builtin_shufflevector(x, x, 1, 0);
}

// Async 16B/lane global->LDS (vmcnt-tracked, zero VGPR while in flight).
// LDS dest = wave-uniform base + lane*16 (HW); global src per-lane.
__device__ __forceinline__ void gld16(const float* g, u4* l) {
  __builtin_amdgcn_global_load_lds(
      (const __attribute__((address_space(1))) void*)g,
      (__attribute__((address_space(3))) void*)l, 16, 0, 0);
}

// Stage one (I,J) row pair into a staging slot: 4 vmem ops.
// Slot layout [img][half][lane] u4; lane l: half0 = cols 8l..8l+3,
// half1 = cols 8l+4..8l+7 (global src pre-swizzled by +8*lane).
// R28 measured: this 16B-lane-stride layout has ZERO bank conflicts.
__device__ __forceinline__ void stage_row(const float* gI, const float* gJ,
                                          u4 (*slot)[2][64], int lane) {
  gld16(gI + 8 * lane, &slot[0][0][0]);
  gld16(gI + 8 * lane + 4, &slot[0][1][0]);
  gld16(gJ + 8 * lane, &slot[1][0][0]);
  gld16(gJ + 8 * lane + 4, &slot[1][1][0]);
}

// Hand-counted wait; "memory" clobber orders surrounding memory ops.
template <int N>
__device__ __forceinline__ void waitcnt_vm() {
  asm volatile("s_waitcnt vmcnt(%0)" ::"i"(N) : "memory");
}

template <class F, int... Ks>
__device__ __forceinline__ void unroll_steps(F&& f,
                                             std::integer_sequence<int, Ks...>) {
  (f(std::integral_constant<int, Ks>{}), ...);
}

// 9-tap centered window sums, 8 contiguous cols/lane (whole 512-col row).
__device__ __forceinline__ void tap8(const h2 u[8], h2 O[8]) {
  const h2 P0 = u[0], P1 = P0 + u[1], P2 = P1 + u[2], P3 = P2 + u[3],
           P4 = P3 + u[4], P5 = P4 + u[5], P6 = P5 + u[6], T = P6 + u[7];
  const h2 UP3 = up1(P3), UP4 = up1(P4), UP5 = up1(P5), UP6 = up1(P6), UT = up1(T);
  const h2 DP0 = dn1(P0), DP1 = dn1(P1), DP2 = dn1(P2), DP3 = dn1(P3);
  O[0] = (UT - UP3) + P4;
  O[1] = (UT - UP4) + P5;
  O[2] = (UT - UP5) + P6;
  O[3] = (UT - UP6) + T;
  O[4] = T + DP0;
  O[5] = (T - P0) + DP1;
  O[6] = (T - P1) + DP2;
  O[7] = (T - P2) + DP3;
}

__global__ __launch_bounds__(64, 1) void ncc_stream(const float* __restrict__ I,
                                                    const float* __restrict__ J,
                                                    float* __restrict__ accum) {
  const int lane = threadIdx.x;
  const int blk = blockIdx.x;
  const int band = blk & (NBAND - 1);
  const int b = blk >> 5;  // batch 0..31
  const int yb = band * YB;
  const h2 zero2 = {_Float16(0.0f), _Float16(0.0f)};
  const h2 ninv81 = {_Float16(-1.0f / 81.0f), _Float16(-1.0f / 81.0f)};

  const float* __restrict__ Ib = I + (size_t)b * (H * W);
  const float* __restrict__ Jb = J + (size_t)b * (H * W);

  // Staging ring: [slot][img][half][lane] u4 = 9 x 4KB = 36KB -> 4 blk/CU.
  __shared__ u4 stg[PFD][2][2][64];

  // mod-9 rings in registers (indices static everywhere; AGPR overflow ok)
  h2 rg[9][8];   // raw ring: (I, J)
  h2 d9[9][8];   // dI/dJ ring: (dI, dJ)
  h2 V[8];       // running vertical sum of raw
  h2 vpq[8];     // (sum dI^2, sum dJ^2)
  h2 vr[8];      // (sum dI*dJ, same)
#pragma unroll
  for (int s = 0; s < 9; ++s)
#pragma unroll
    for (int c = 0; c < 8; ++c) { rg[s][c] = zero2; d9[s][c] = zero2; }
#pragma unroll
  for (int c = 0; c < 8; ++c) { V[c] = zero2; vpq[c] = zero2; vr[c] = zero2; }
  float acc = 0.f;

  // Prologue: stage rows yb-8 .. yb (9 rows; low clamp only, max yb=496).
#pragma unroll
  for (int j = 0; j < PFD; ++j) {
    const int y0 = yb - 8 + j;
    const int yc0 = y0 < 0 ? 0 : y0;
    stage_row(Ib + yc0 * W, Jb + yc0 * W, stg[j], lane);
  }

  // One step. J/ALW/ISSUE compile-time; k,y runtime (wave-uniform).
  // vmcnt proof: issued before wait at step k = 36 + 4*min(k,23); consumed
  // slot's ops are indices 4k..4k+3; newer ops = 36+4*min(k,23)-(4k+4)
  // -> k<=22: 32 (steady); k=23..31: 124-4k (tail literals).
  auto step = [&](auto Jc, auto Wc, auto Ic, int k, int y) {
    constexpr int J = decltype(Jc)::value;
    constexpr int t = (J + 5) % 9;  // center slot (row y-4)
    constexpr int ALW = decltype(Wc)::value;
    constexpr bool ISSUE = decltype(Ic)::value;
    const unsigned msk = ((y >= 0) & (y < H)) ? 0xFFFFFFFFu : 0u;

    // 0) wait: slot J's 4 gld_lds (issued 9 steps ago / prologue) landed
    waitcnt_vm<ALW>();

    // 1) consume slot J (b128 x4, 16B lane stride), pack, AND-mask y-pad
    const float4 ia = *reinterpret_cast<const float4*>(&stg[J][0][0][lane]);
    const float4 ix = *reinterpret_cast<const float4*>(&stg[J][0][1][lane]);
    const float4 ja = *reinterpret_cast<const float4*>(&stg[J][1][0][lane]);
    const float4 jx = *reinterpret_cast<const float4*>(&stg[J][1][1][lane]);
    h2 na[8];
    na[0] = pkm(ia.x, ja.x, msk);
    na[1] = pkm(ia.y, ja.y, msk);
    na[2] = pkm(ia.z, ja.z, msk);
    na[3] = pkm(ia.w, ja.w, msk);
    na[4] = pkm(ix.x, jx.x, msk);
    na[5] = pkm(ix.y, jx.y, msk);
    na[6] = pkm(ix.z, jx.z, msk);
    na[7] = pkm(ix.w, jx.w, msk);

    // 2) reissue slot J for row y+9 (consumed at step k+9; upper clamp only,
    //    y+9 >= yb+1 >= 1; masked pkm fixes overshoot values)
    if constexpr (ISSUE) {
      const int yn = y + 9;
      const int ycn = yn > H - 1 ? H - 1 : yn;
      stage_row(Ib + ycn * W, Jb + ycn * W, stg[J], lane);
    }

    // 3) vertical running sum: evict slot J (row y-9), write new
#pragma unroll
    for (int c = 0; c < 8; ++c) {
      V[c] += na[c] - rg[J][c];
      rg[J][c] = na[c];
    }

    if (k >= 8) {  // wave-uniform (folded in tail)
      const int mrow = y - 4;
      if ((mrow >= 0) & (mrow < H)) {  // wave-uniform
        h2 M[8];
        tap8(V, M);
#pragma unroll
        for (int c = 0; c < 8; ++c) {
          const h2 d = M[c] * ninv81 + rg[t][c];  // (dI, dJ)
          const h2 o = d9[t][c];
          vpq[c] += d * d - o * o;                // (dI^2, dJ^2)
          vr[c] += d * swp(d) - o * swp(o);       // (dI*dJ, dI*dJ)
          d9[t][c] = d;
        }
      } else {  // mrow outside image: dI=dJ=0, eviction-only
#pragma unroll
        for (int c = 0; c < 8; ++c) {
          const h2 o = d9[t][c];
          vpq[c] -= o * o;
          vr[c] -= o * swp(o);
          d9[t][c] = zero2;
        }
      }

      if (k >= 16) {  // wave-uniform (folded in tail)
        h2 P[8], R[8];
        tap8(vpq, P);  // (81^2 varI, 81^2 varJ) pre-scale
        tap8(vr, R);   // (81^2 cov, same)
#pragma unroll
        for (int c = 0; c < 8; ++c) {
          const float Pl = (float)P[c][0], Qh = (float)P[c][1];
          const float Rl = (float)R[c][0];
          acc += (Rl * Rl) * __builtin_amdgcn_rcpf(fmaf(Pl, Qh, EPS81));
        }
      }
    }
  };

  // Head: k=0..17, ROLLED over two 9-step macros (one body in code).
#pragma unroll 1
  for (int mm = 0; mm < 2; ++mm) {
    unroll_steps(
        [&](auto jc) {
          constexpr int J = decltype(jc)::value;
          const int k = 9 * mm + J;
          step(jc, std::integral_constant<int, 32>{},
               std::integral_constant<bool, true>{}, k, yb - 8 + k);
        },
        std::make_integer_sequence<int, 9>{});
  }
  // Tail: k=18..31 unrolled; issue stops after k=22; exact drain literals.
  unroll_steps(
      [&](auto kc) {
        constexpr int K = 18 + decltype(kc)::value;
        constexpr int J = K % 9;
        constexpr int ALW = (K <= 22) ? 32 : (124 - 4 * K);
        step(std::integral_constant<int, J>{},
             std::integral_constant<int, ALW>{},
             std::integral_constant<bool, (K <= 22)>{}, K, yb - 8 + K);
      },
      std::make_integer_sequence<int, 14>{});

  // wave reduction, one atomic per wave
#pragma unroll
  for (int off = 32; off > 0; off >>= 1) acc += __shfl_down(acc, off, 64);
  if (lane == 0) atomicAdd(accum, acc);
}

__global__ void finalize(const float* __restrict__ ws, float* __restrict__ out) {
  out[0] = -ws[0] * (1.0f / (float)((size_t)BATCH * H * W));
}

extern "C" void kernel_launch(void* const* d_in, const int* in_sizes, int n_in,
                              void* d_out, int out_size, void* d_ws, size_t ws_size,
                              hipStream_t stream) {
  const float* I = (const float*)d_in[0];
  const float* J = (const float*)d_in[1];
  float* out = (float*)d_out;
  float* acc = (float*)d_ws;

  zero_accum<<<1, 1, 0, stream>>>(acc);
  ncc_stream<<<BATCH * NBAND, 64, 0, stream>>>(I, J, acc);
  finalize<<<1, 1, 0, stream>>>(acc, out);
}